// Round 2
// baseline (324.146 us; speedup 1.0000x reference)
//
#include <hip/hip_runtime.h>
#include <hip/hip_cooperative_groups.h>

namespace cg = cooperative_groups;

#define N_TOK 576          // 24*24 patches per image
#define HP    24
#define PS    16
#define IMG   384
#define ATTN_SCALE 0.35355339059327373f   // 8^-0.5

struct Params {
    const float *x;
    const float *Wq, *bq, *Wk, *bk, *Wv, *bv;
    const float *Wsq, *bsq, *Wsk, *bsk, *Wsv, *bsv;
    const float *ln_g, *ln_b, *Wp, *bp;
    float *q1, *k1, *v1, *q2, *k2, *v2;
    int  *smax;
    float *out;
};

// Block-wide attention over 576 keys, HID=8. All 256 threads participate;
// returns the normalized context vector f[8] to every thread.
// Uses lds[0..39]. Trailing __syncthreads() makes back-to-back calls safe.
__device__ __forceinline__ void block_attn(
    const float* __restrict__ qrow, const float* __restrict__ kb,
    const float* __restrict__ vb, float* lds, float f[8])
{
    const int t = threadIdx.x, lane = t & 63, wv = t >> 6;
    float qv[8];
#pragma unroll
    for (int h = 0; h < 8; ++h) qv[h] = qrow[h];

    // each thread owns keys {t, t+256, t+512(<576)}
    float sc[3], mx = -1e30f;
#pragma unroll
    for (int r = 0; r < 3; ++r) {
        const int idx = t + r*256;
        if (idx < N_TOK) {
            const float* kp = kb + idx*8;
            float d = 0.f;
#pragma unroll
            for (int h = 0; h < 8; ++h) d += qv[h]*kp[h];
            sc[r] = d * ATTN_SCALE;
            mx = fmaxf(mx, sc[r]);
        }
    }
#pragma unroll
    for (int off = 32; off; off >>= 1) mx = fmaxf(mx, __shfl_xor(mx, off));
    if (lane == 0) lds[wv] = mx;                  // lds[0..3]
    __syncthreads();
    mx = fmaxf(fmaxf(lds[0], lds[1]), fmaxf(lds[2], lds[3]));

    float o[9];                                    // o[0..7]=PV, o[8]=sum(p)
#pragma unroll
    for (int j = 0; j < 9; ++j) o[j] = 0.f;
#pragma unroll
    for (int r = 0; r < 3; ++r) {
        const int idx = t + r*256;
        if (idx < N_TOK) {
            const float pw = __expf(sc[r] - mx);
            o[8] += pw;
            const float* vp = vb + idx*8;
#pragma unroll
            for (int h = 0; h < 8; ++h) o[h] += pw*vp[h];
        }
    }
#pragma unroll
    for (int off = 32; off; off >>= 1)
#pragma unroll
        for (int j = 0; j < 9; ++j) o[j] += __shfl_xor(o[j], off);
    if (lane == 0)
#pragma unroll
        for (int j = 0; j < 9; ++j) lds[4 + wv*9 + j] = o[j];   // lds[4..39]
    __syncthreads();
    float tot[9];
#pragma unroll
    for (int j = 0; j < 9; ++j)
        tot[j] = lds[4+j] + lds[13+j] + lds[22+j] + lds[31+j];
    const float inv = 1.f / tot[8];
#pragma unroll
    for (int h = 0; h < 8; ++h) f[h] = tot[h]*inv;
    __syncthreads();   // safe re-entry: next call rewrites lds[0..39]
}

// Fully fused pipeline. grid = 576 blocks x 256 threads (cooperative).
// Block n owns patch n of BOTH batch images (bi = 0,1 loops per phase) —
// only 3 blocks/CU co-residency needed; __launch_bounds__(256,4) caps VGPR
// at 128 -> runtime occupancy >= 4 blocks/CU = 1024 >= 576. Headroom 2x.
__global__ __launch_bounds__(256, 4) void k_fused(Params p)
{
    // [0..1279] bilateral tile (stride 40), [1280..1568] spatial-weight table.
    // Phases A-C reuse [0..95] for reductions (barriers separate uses).
    __shared__ float lds[1572];
    __shared__ float s_sig[2][3];
    __shared__ int   s_half;

    const int t = threadIdx.x;
    const int lane = t & 63, wv = t >> 6;
    const int n = blockIdx.x;              // 0..575 patch index
    const int py = n / HP, px = n % HP;

    cg::grid_group grid = cg::this_grid();

    // ---------------- Phase A: patchify + QKV1 (256 -> 8, x3), both imgs --
    if (n == 0 && t == 0) *p.smax = 0;     // replaces hipMemsetAsync
    {
        const int iy = t >> 4, ix = t & 15;
#pragma unroll
        for (int bi = 0; bi < 2; ++bi) {
            const float pv = p.x[bi*IMG*IMG + (py*PS + iy)*IMG + (px*PS + ix)];
            float acc[24];
#pragma unroll
            for (int h = 0; h < 8; ++h) {
                acc[h]      = pv * p.Wq[t*8 + h];
                acc[8 + h]  = pv * p.Wk[t*8 + h];
                acc[16 + h] = pv * p.Wv[t*8 + h];
            }
#pragma unroll
            for (int off = 32; off; off >>= 1)
#pragma unroll
                for (int j = 0; j < 24; ++j) acc[j] += __shfl_down(acc[j], off);
            if (lane == 0)
#pragma unroll
                for (int j = 0; j < 24; ++j) lds[wv*24 + j] = acc[j];
            __syncthreads();
            if (t < 24) {
                const float s = lds[t] + lds[24+t] + lds[48+t] + lds[72+t];
                const int h = t & 7, mat = t >> 3;
                const float* bias = (mat==0) ? p.bq : (mat==1) ? p.bk : p.bv;
                float* dst = (mat==0) ? p.q1 : (mat==1) ? p.k1 : p.v1;
                dst[(bi*N_TOK + n)*8 + h] = s + bias[h];
            }
            __syncthreads();               // WAR before next bi reuses lds
        }
    }
    grid.sync();

    // ---------------- Phase B: attention 1 + QKV2 projection, both imgs ---
#pragma unroll
    for (int bi = 0; bi < 2; ++bi) {
        const int tok = bi*N_TOK + n;
        float f[8];
        block_attn(p.q1 + tok*8, p.k1 + bi*N_TOK*8, p.v1 + bi*N_TOK*8, lds, f);
        if (t < 24) {
            const int mat = t >> 3, h = t & 7;
            const float* Wm = (mat==0)?p.Wsq:(mat==1)?p.Wsk:p.Wsv;
            const float* bm = (mat==0)?p.bsq:(mat==1)?p.bsk:p.bsv;
            float s = bm[h];
#pragma unroll
            for (int j = 0; j < 8; ++j) s += f[j]*Wm[j*8 + h];
            float* dst = (mat==0)?p.q2:(mat==1)?p.k2:p.v2;
            dst[tok*8 + h] = s;
        }
    }
    grid.sync();

    // ---------------- Phase C: attention 2 + LN + BoundedSoftplus ---------
#pragma unroll
    for (int bi = 0; bi < 2; ++bi) {
        const int tok = bi*N_TOK + n;
        float f[8];
        block_attn(p.q2 + tok*8, p.k2 + bi*N_TOK*8, p.v2 + bi*N_TOK*8, lds, f);
        if (t == 0) {
            float mu = 0.f;
#pragma unroll
            for (int h = 0; h < 8; ++h) mu += f[h];
            mu *= 0.125f;
            float var = 0.f;
#pragma unroll
            for (int h = 0; h < 8; ++h) { const float d = f[h]-mu; var += d*d; }
            var *= 0.125f;
            const float rinv = rsqrtf(var + 1e-5f);
            float on[8];
#pragma unroll
            for (int h = 0; h < 8; ++h)
                on[h] = (f[h]-mu)*rinv*p.ln_g[h] + p.ln_b[h];
            float sv[3];
#pragma unroll
            for (int c = 0; c < 3; ++c) {
                float z = p.bp[c];
#pragma unroll
                for (int j = 0; j < 8; ++j) z += on[j]*p.Wp[j*3 + c];
                const float sp = (z > 20.f) ? z : log1pf(__expf(z));
                sv[c] = fminf(sp, 6.0f) + 1e-6f;
                s_sig[bi][c] = sv[c];            // sigmas stay in LDS
            }
            atomicMax(p.smax, __float_as_int(fmaxf(sv[0], sv[1])));
        }
    }
    grid.sync();

    // ---------------- Phase D: half + bilateral filter, both imgs ---------
    {
        if (t == 0) {
            const int mi = atomicMax(p.smax, 0);   // coherent cross-XCD read
            const float m = __int_as_float(mi);
            int h = (int)ceilf(m + 1.0f);
            if (h < 1) h = 1;
            if (h > 8) h = 8;        // sigma cap 6 -> h <= 8; guards LDS tile
            s_half = h;
        }
        __syncthreads();
        const int half = s_half;
        const int k = 2*half + 1;
        const int tilew = PS + 2*half;           // <= 32
        const int tx = t & 15, ty = t >> 4;
        float* tile = lds;                        // stride 40: free 2-way banks
        float* spt  = lds + 1280;                 // k*k <= 289 spatial weights

        for (int bi = 0; bi < 2; ++bi) {
            const float sx = s_sig[bi][0], sy = s_sig[bi][1], sr = s_sig[bi][2];
            const float* xb = p.x + bi*IMG*IMG;

            for (int yy = ty; yy < tilew; yy += 16) {
                const int gy = py*PS + yy - half;
                for (int xx = tx; xx < tilew; xx += 16) {
                    const int gx = px*PS + xx - half;
                    float v = 0.f;                // zero padding in sums
                    if ((unsigned)gy < IMG && (unsigned)gx < IMG)
                        v = xb[gy*IMG + gx];
                    tile[yy*40 + xx] = v;
                }
            }
            const float axc = -0.5f/(sx*sx);
            const float ayc = -0.5f/(sy*sy);
            for (int i = t; i < k*k; i += 256) {
                const int dy = i / k, dx = i - dy*k;
                const float fy = (float)(dy - half), fx = (float)(dx - half);
                spt[i] = __expf(ayc*fy*fy + axc*fx*fx);
            }
            __syncthreads();

            const float c   = tile[(ty+half)*40 + (tx+half)];
            const float ar2 = -0.72134752044448170f/(sr*sr); // -0.5*log2e/sr^2
            float num = 0.f, den = 0.f;
            for (int dy = 0; dy < k; ++dy) {
                const float* row = &tile[(ty+dy)*40 + tx];
                const float* spr = &spt[dy*k];     // uniform -> LDS broadcast
                for (int dx = 0; dx < k; ++dx) {
                    const float pix = row[dx];
                    const float d   = c - pix;
                    const float w   = spr[dx] * exp2f(ar2*d*d);
                    den += w;
                    num += w*pix;
                }
            }
            p.out[bi*IMG*IMG + (py*PS + ty)*IMG + (px*PS + tx)] =
                num/(den + 1e-8f);
            __syncthreads();                       // WAR before next bi tile
        }
    }
}

// ======================= fallback path (non-cooperative) ====================
__global__ __launch_bounds__(256) void k_qkv1(
    const float* __restrict__ x,
    const float* __restrict__ Wq, const float* __restrict__ bq,
    const float* __restrict__ Wk, const float* __restrict__ bk,
    const float* __restrict__ Wv, const float* __restrict__ bv,
    float* __restrict__ q1, float* __restrict__ k1, float* __restrict__ v1,
    int* __restrict__ smax)
{
    const int blk = blockIdx.x;           // b*576 + n
    const int b  = blk / N_TOK;
    const int n  = blk % N_TOK;
    const int py = n / HP, px = n % HP;
    const int t  = threadIdx.x;
    const int iy = t >> 4, ix = t & 15;

    if (blk == 0 && t == 0) *smax = 0;    // replaces memset dispatch

    const float pv = x[b*IMG*IMG + (py*PS + iy)*IMG + (px*PS + ix)];

    float acc[24];
#pragma unroll
    for (int h = 0; h < 8; ++h) {
        acc[h]      = pv * Wq[t*8 + h];
        acc[8 + h]  = pv * Wk[t*8 + h];
        acc[16 + h] = pv * Wv[t*8 + h];
    }
#pragma unroll
    for (int off = 32; off; off >>= 1)
#pragma unroll
        for (int j = 0; j < 24; ++j) acc[j] += __shfl_down(acc[j], off);
    __shared__ float red[4][24];
    const int lane = t & 63, w = t >> 6;
    if (lane == 0)
#pragma unroll
        for (int j = 0; j < 24; ++j) red[w][j] = acc[j];
    __syncthreads();
    if (t < 24) {
        float s = red[0][t] + red[1][t] + red[2][t] + red[3][t];
        const int h = t & 7, mat = t >> 3;
        const float* bias = (mat == 0) ? bq : (mat == 1) ? bk : bv;
        float* dst = (mat == 0) ? q1 : (mat == 1) ? k1 : v1;
        dst[(b*N_TOK + n)*8 + h] = s + bias[h];
    }
}

__global__ __launch_bounds__(256) void k_attn1(
    const float* __restrict__ q1, const float* __restrict__ k1, const float* __restrict__ v1,
    const float* __restrict__ Wsq, const float* __restrict__ bsq,
    const float* __restrict__ Wsk, const float* __restrict__ bsk,
    const float* __restrict__ Wsv, const float* __restrict__ bsv,
    float* __restrict__ q2, float* __restrict__ k2, float* __restrict__ v2)
{
    const int lane = threadIdx.x & 63;
    const int wv   = threadIdx.x >> 6;
    const int tok  = blockIdx.x*4 + wv;
    const int b    = tok / N_TOK;

    float qv[8];
#pragma unroll
    for (int h = 0; h < 8; ++h) qv[h] = q1[tok*8 + h];
    const float* kb = k1 + b*N_TOK*8;
    const float* vb = v1 + b*N_TOK*8;

    float sc[9], mx = -1e30f;
#pragma unroll
    for (int ch = 0; ch < 9; ++ch) {
        const float* kp = kb + (ch*64 + lane)*8;
        float d = 0.f;
#pragma unroll
        for (int h = 0; h < 8; ++h) d += qv[h]*kp[h];
        d *= ATTN_SCALE;
        sc[ch] = d;
        mx = fmaxf(mx, d);
    }
#pragma unroll
    for (int off = 32; off; off >>= 1) mx = fmaxf(mx, __shfl_xor(mx, off));

    float ssum = 0.f, o[8];
#pragma unroll
    for (int h = 0; h < 8; ++h) o[h] = 0.f;
#pragma unroll
    for (int ch = 0; ch < 9; ++ch) {
        const float pw = __expf(sc[ch] - mx);
        ssum += pw;
        const float* vp = vb + (ch*64 + lane)*8;
#pragma unroll
        for (int h = 0; h < 8; ++h) o[h] += pw*vp[h];
    }
#pragma unroll
    for (int off = 32; off; off >>= 1) {
        ssum += __shfl_xor(ssum, off);
#pragma unroll
        for (int h = 0; h < 8; ++h) o[h] += __shfl_xor(o[h], off);
    }
    const float inv = 1.f/ssum;
    float f[8];
#pragma unroll
    for (int h = 0; h < 8; ++h) f[h] = o[h]*inv;

    if (lane < 24) {
        const int mat = lane >> 3, h = lane & 7;
        const float* Wm = (mat==0)?Wsq:(mat==1)?Wsk:Wsv;
        const float* bm = (mat==0)?bsq:(mat==1)?bsk:bsv;
        float s = bm[h];
#pragma unroll
        for (int j = 0; j < 8; ++j) s += f[j]*Wm[j*8 + h];
        float* dst = (mat==0)?q2:(mat==1)?k2:v2;
        dst[tok*8 + h] = s;
    }
}

__global__ __launch_bounds__(256) void k_attn2(
    const float* __restrict__ q2, const float* __restrict__ k2, const float* __restrict__ v2,
    const float* __restrict__ ln_g, const float* __restrict__ ln_b,
    const float* __restrict__ Wp,   const float* __restrict__ bp,
    float* __restrict__ sig, int* __restrict__ smax)
{
    const int lane = threadIdx.x & 63;
    const int wv   = threadIdx.x >> 6;
    const int tok  = blockIdx.x*4 + wv;
    const int b    = tok / N_TOK;

    float qv[8];
#pragma unroll
    for (int h = 0; h < 8; ++h) qv[h] = q2[tok*8 + h];
    const float* kb = k2 + b*N_TOK*8;
    const float* vb = v2 + b*N_TOK*8;

    float sc[9], mx = -1e30f;
#pragma unroll
    for (int ch = 0; ch < 9; ++ch) {
        const float* kp = kb + (ch*64 + lane)*8;
        float d = 0.f;
#pragma unroll
        for (int h = 0; h < 8; ++h) d += qv[h]*kp[h];
        d *= ATTN_SCALE;
        sc[ch] = d;
        mx = fmaxf(mx, d);
    }
#pragma unroll
    for (int off = 32; off; off >>= 1) mx = fmaxf(mx, __shfl_xor(mx, off));

    float ssum = 0.f, o[8];
#pragma unroll
    for (int h = 0; h < 8; ++h) o[h] = 0.f;
#pragma unroll
    for (int ch = 0; ch < 9; ++ch) {
        const float pw = __expf(sc[ch] - mx);
        ssum += pw;
        const float* vp = vb + (ch*64 + lane)*8;
#pragma unroll
        for (int h = 0; h < 8; ++h) o[h] += pw*vp[h];
    }
#pragma unroll
    for (int off = 32; off; off >>= 1) {
        ssum += __shfl_xor(ssum, off);
#pragma unroll
        for (int h = 0; h < 8; ++h) o[h] += __shfl_xor(o[h], off);
    }

    if (lane == 0) {
        const float inv = 1.f/ssum;
        float f[8];
        float mu = 0.f;
#pragma unroll
        for (int h = 0; h < 8; ++h) { f[h] = o[h]*inv; mu += f[h]; }
        mu *= 0.125f;
        float var = 0.f;
#pragma unroll
        for (int h = 0; h < 8; ++h) { const float d = f[h]-mu; var += d*d; }
        var *= 0.125f;
        const float rinv = rsqrtf(var + 1e-5f);
        float on[8];
#pragma unroll
        for (int h = 0; h < 8; ++h)
            on[h] = (f[h]-mu)*rinv*ln_g[h] + ln_b[h];
        float sv[3];
#pragma unroll
        for (int c = 0; c < 3; ++c) {
            float z = bp[c];
#pragma unroll
            for (int j = 0; j < 8; ++j) z += on[j]*Wp[j*3 + c];
            const float sp = (z > 20.f) ? z : log1pf(__expf(z));
            sv[c] = fminf(sp, 6.0f) + 1e-6f;
            sig[tok*3 + c] = sv[c];
        }
        atomicMax(smax, __float_as_int(fmaxf(sv[0], sv[1])));
    }
}

__global__ __launch_bounds__(256) void k_bilat(
    const float* __restrict__ x, const float* __restrict__ sig,
    int* __restrict__ smax, float* __restrict__ out)
{
    __shared__ float tile[32*40];
    __shared__ int s_half;
    const int blk = blockIdx.x;           // b*576 + n
    const int b  = blk / N_TOK;
    const int n  = blk % N_TOK;
    const int py = n / HP, px = n % HP;
    const int tx = threadIdx.x & 15, ty = threadIdx.x >> 4;

    if (threadIdx.x == 0) {
        const float m = __int_as_float(atomicMax(smax, 0));
        int h = (int)ceilf(m + 1.0f);
        if (h < 1) h = 1;
        if (h > 8) h = 8;
        s_half = h;
    }
    __syncthreads();
    const int half = s_half;
    const float sx = sig[blk*3 + 0];
    const float sy = sig[blk*3 + 1];
    const float sr = sig[blk*3 + 2];

    const int tilew = PS + 2*half;
    const float* xb = x + b*IMG*IMG;
    for (int yy = ty; yy < tilew; yy += 16) {
        const int gy = py*PS + yy - half;
        for (int xx = tx; xx < tilew; xx += 16) {
            const int gx = px*PS + xx - half;
            float v = 0.f;
            if ((unsigned)gy < IMG && (unsigned)gx < IMG)
                v = xb[gy*IMG + gx];
            tile[yy*40 + xx] = v;
        }
    }
    __syncthreads();

    const float c  = tile[(ty+half)*40 + (tx+half)];
    const float ax = -0.5f/(sx*sx);
    const float ay = -0.5f/(sy*sy);
    const float ar = -0.5f/(sr*sr);

    float num = 0.f, den = 0.f;
    const int k = 2*half + 1;
    for (int dy = 0; dy < k; ++dy) {
        const float fy = (float)(dy - half);
        const float ey = ay*fy*fy;
        const float* row = &tile[(ty+dy)*40 + tx];
        for (int dx = 0; dx < k; ++dx) {
            const float fx = (float)(dx - half);
            const float pix = row[dx];
            const float d  = c - pix;
            const float w  = __expf(ey + ax*fx*fx + ar*d*d);
            den += w;
            num += w*pix;
        }
    }
    out[b*IMG*IMG + (py*PS + ty)*IMG + (px*PS + tx)] = num/(den + 1e-8f);
}

// ---------------- launch ---------------------------------------------------
extern "C" void kernel_launch(void* const* d_in, const int* in_sizes, int n_in,
                              void* d_out, int out_size, void* d_ws, size_t ws_size,
                              hipStream_t stream)
{
    Params p;
    p.x    = (const float*)d_in[0];
    p.Wq   = (const float*)d_in[1];
    p.bq   = (const float*)d_in[2];
    p.Wk   = (const float*)d_in[3];
    p.bk   = (const float*)d_in[4];
    p.Wv   = (const float*)d_in[5];
    p.bv   = (const float*)d_in[6];
    p.Wsq  = (const float*)d_in[7];
    p.bsq  = (const float*)d_in[8];
    p.Wsk  = (const float*)d_in[9];
    p.bsk  = (const float*)d_in[10];
    p.Wsv  = (const float*)d_in[11];
    p.bsv  = (const float*)d_in[12];
    p.ln_g = (const float*)d_in[13];
    p.ln_b = (const float*)d_in[14];
    p.Wp   = (const float*)d_in[15];
    p.bp   = (const float*)d_in[16];

    float* W = (float*)d_ws;
    p.q1 = W;                 // 2*576*8 = 9216 floats each
    p.k1 = W +  9216;
    p.v1 = W + 18432;
    p.q2 = W + 27648;
    p.k2 = W + 36864;
    p.v2 = W + 46080;
    float* sg = W + 55296;    // 2*576*3 (fallback only)
    p.smax = (int*)(W + 58752);
    p.out  = (float*)d_out;

    void* args[] = { &p };
    hipError_t err = hipLaunchCooperativeKernel((void*)k_fused, dim3(N_TOK),
                                                dim3(256), args, 0, stream);
    if (err != hipSuccess) {
        // cooperative launch refused (occupancy / capture) -> 4-dispatch path
        k_qkv1<<<2*N_TOK, 256, 0, stream>>>(p.x, p.Wq, p.bq, p.Wk, p.bk,
                                            p.Wv, p.bv, p.q1, p.k1, p.v1,
                                            p.smax);
        k_attn1<<<2*N_TOK/4, 256, 0, stream>>>(p.q1, p.k1, p.v1,
                                               p.Wsq, p.bsq, p.Wsk, p.bsk,
                                               p.Wsv, p.bsv, p.q2, p.k2, p.v2);
        k_attn2<<<2*N_TOK/4, 256, 0, stream>>>(p.q2, p.k2, p.v2,
                                               p.ln_g, p.ln_b, p.Wp, p.bp,
                                               sg, p.smax);
        k_bilat<<<2*N_TOK, 256, 0, stream>>>(p.x, sg, p.smax, p.out);
    }
}

// Round 4
// 149.646 us; speedup vs baseline: 2.1661x; 2.1661x over previous
//
#include <hip/hip_runtime.h>

#define N_TOK 576          // 24*24 patches per image
#define HP    24
#define PS    16
#define IMG   384
#define ATTN_SCALE 0.35355339059327373f   // 8^-0.5

// ---------------- K1: patchify + first QKV projection (256 -> 8, x3) -------
// One WAVE per patch (4 patches/block). Lane l owns feature indices
// 4l..4l+3 (= pixel row l>>2, cols (l&3)*4 + j) -> float4 coalesced load,
// and reads Wq/Wk/Wv rows 4l..4l+3 = 128 contiguous bytes per lane.
__global__ __launch_bounds__(256) void k_qkv1(
    const float* __restrict__ x,
    const float* __restrict__ Wq, const float* __restrict__ bq,
    const float* __restrict__ Wk, const float* __restrict__ bk,
    const float* __restrict__ Wv, const float* __restrict__ bv,
    float* __restrict__ q1, float* __restrict__ k1, float* __restrict__ v1,
    int* __restrict__ smax)
{
    const int lane = threadIdx.x & 63, wv = threadIdx.x >> 6;
    const int idx = blockIdx.x*4 + wv;        // 0..1151 = b*576 + n
    const int b = idx / N_TOK, n = idx % N_TOK;
    const int py = n / HP, px = n % HP;

    // replaces the old memset dispatch; atomic -> coherent across XCDs
    if (idx == 0 && lane == 0) atomicExch(smax, 0);

    const int iy = lane >> 2, ix0 = (lane & 3) * 4;
    const float4 pv = *(const float4*)
        &x[b*IMG*IMG + (py*PS + iy)*IMG + px*PS + ix0];

    float acc[24];
#pragma unroll
    for (int j = 0; j < 24; ++j) acc[j] = 0.f;

#pragma unroll
    for (int j = 0; j < 4; ++j) {
        const int t = 4*lane + j;             // feature index, row of W
        const float p = ((const float*)&pv)[j];
#pragma unroll
        for (int h = 0; h < 8; ++h) {
            acc[h]      += p * Wq[t*8 + h];
            acc[8 + h]  += p * Wk[t*8 + h];
            acc[16 + h] += p * Wv[t*8 + h];
        }
    }
#pragma unroll
    for (int off = 32; off; off >>= 1)
#pragma unroll
        for (int j = 0; j < 24; ++j) acc[j] += __shfl_xor(acc[j], off);

    if (lane == 0) {
#pragma unroll
        for (int h = 0; h < 8; ++h) {
            q1[idx*8 + h] = acc[h]      + bq[h];
            k1[idx*8 + h] = acc[8 + h]  + bk[h];
            v1[idx*8 + h] = acc[16 + h] + bv[h];
        }
    }
}

// ---------------- K2: attention 1 + fused QKV2 projection ------------------
// one wave per token; 576 keys = 9 chunks of 64; K/V rows loaded as float4x2
__global__ __launch_bounds__(256) void k_attn1(
    const float* __restrict__ q1, const float* __restrict__ k1, const float* __restrict__ v1,
    const float* __restrict__ Wsq, const float* __restrict__ bsq,
    const float* __restrict__ Wsk, const float* __restrict__ bsk,
    const float* __restrict__ Wsv, const float* __restrict__ bsv,
    float* __restrict__ q2, float* __restrict__ k2, float* __restrict__ v2)
{
    const int lane = threadIdx.x & 63;
    const int wv   = threadIdx.x >> 6;
    const int tok  = blockIdx.x*4 + wv;     // 0..1151
    const int b    = tok / N_TOK;

    const float4 qa = *(const float4*)&q1[tok*8];
    const float4 qb = *(const float4*)&q1[tok*8 + 4];

    const float* kbp = k1 + b*N_TOK*8;
    const float* vbp = v1 + b*N_TOK*8;

    float sc[9], mx = -1e30f;
#pragma unroll
    for (int ch = 0; ch < 9; ++ch) {
        const float4* kp = (const float4*)(kbp + (ch*64 + lane)*8);
        const float4 k0 = kp[0], k1v = kp[1];
        float d = qa.x*k0.x + qa.y*k0.y + qa.z*k0.z + qa.w*k0.w
                + qb.x*k1v.x + qb.y*k1v.y + qb.z*k1v.z + qb.w*k1v.w;
        d *= ATTN_SCALE;
        sc[ch] = d;
        mx = fmaxf(mx, d);
    }
#pragma unroll
    for (int off = 32; off; off >>= 1) mx = fmaxf(mx, __shfl_xor(mx, off));

    float ssum = 0.f, o[8];
#pragma unroll
    for (int h = 0; h < 8; ++h) o[h] = 0.f;
#pragma unroll
    for (int ch = 0; ch < 9; ++ch) {
        const float p = __expf(sc[ch] - mx);
        ssum += p;
        const float4* vp = (const float4*)(vbp + (ch*64 + lane)*8);
        const float4 v0 = vp[0], v1v = vp[1];
        o[0] += p*v0.x; o[1] += p*v0.y; o[2] += p*v0.z; o[3] += p*v0.w;
        o[4] += p*v1v.x; o[5] += p*v1v.y; o[6] += p*v1v.z; o[7] += p*v1v.w;
    }
#pragma unroll
    for (int off = 32; off; off >>= 1) {
        ssum += __shfl_xor(ssum, off);
#pragma unroll
        for (int h = 0; h < 8; ++h) o[h] += __shfl_xor(o[h], off);
    }
    const float inv = 1.f/ssum;
    float f[8];
#pragma unroll
    for (int h = 0; h < 8; ++h) f[h] = o[h]*inv;

    if (lane < 24) {
        const int mat = lane >> 3, h = lane & 7;
        const float* Wm = (mat==0)?Wsq:(mat==1)?Wsk:Wsv;
        const float* bm = (mat==0)?bsq:(mat==1)?bsk:bsv;
        float s = bm[h];
#pragma unroll
        for (int j = 0; j < 8; ++j) s += f[j]*Wm[j*8 + h];
        float* dst = (mat==0)?q2:(mat==1)?k2:v2;
        dst[tok*8 + h] = s;
    }
}

// ---------------- K3: attention 2 + LayerNorm + BoundedSoftplus sigmas -----
__global__ __launch_bounds__(256) void k_attn2(
    const float* __restrict__ q2, const float* __restrict__ k2, const float* __restrict__ v2,
    const float* __restrict__ ln_g, const float* __restrict__ ln_b,
    const float* __restrict__ Wp,   const float* __restrict__ bp,
    float* __restrict__ sig, int* __restrict__ smax)
{
    const int lane = threadIdx.x & 63;
    const int wv   = threadIdx.x >> 6;
    const int tok  = blockIdx.x*4 + wv;
    const int b    = tok / N_TOK;

    const float4 qa = *(const float4*)&q2[tok*8];
    const float4 qb = *(const float4*)&q2[tok*8 + 4];

    const float* kbp = k2 + b*N_TOK*8;
    const float* vbp = v2 + b*N_TOK*8;

    float sc[9], mx = -1e30f;
#pragma unroll
    for (int ch = 0; ch < 9; ++ch) {
        const float4* kp = (const float4*)(kbp + (ch*64 + lane)*8);
        const float4 k0 = kp[0], k1v = kp[1];
        float d = qa.x*k0.x + qa.y*k0.y + qa.z*k0.z + qa.w*k0.w
                + qb.x*k1v.x + qb.y*k1v.y + qb.z*k1v.z + qb.w*k1v.w;
        d *= ATTN_SCALE;
        sc[ch] = d;
        mx = fmaxf(mx, d);
    }
#pragma unroll
    for (int off = 32; off; off >>= 1) mx = fmaxf(mx, __shfl_xor(mx, off));

    float ssum = 0.f, o[8];
#pragma unroll
    for (int h = 0; h < 8; ++h) o[h] = 0.f;
#pragma unroll
    for (int ch = 0; ch < 9; ++ch) {
        const float p = __expf(sc[ch] - mx);
        ssum += p;
        const float4* vp = (const float4*)(vbp + (ch*64 + lane)*8);
        const float4 v0 = vp[0], v1v = vp[1];
        o[0] += p*v0.x; o[1] += p*v0.y; o[2] += p*v0.z; o[3] += p*v0.w;
        o[4] += p*v1v.x; o[5] += p*v1v.y; o[6] += p*v1v.z; o[7] += p*v1v.w;
    }
#pragma unroll
    for (int off = 32; off; off >>= 1) {
        ssum += __shfl_xor(ssum, off);
#pragma unroll
        for (int h = 0; h < 8; ++h) o[h] += __shfl_xor(o[h], off);
    }

    if (lane == 0) {
        const float inv = 1.f/ssum;
        float f[8];
        float mu = 0.f;
#pragma unroll
        for (int h = 0; h < 8; ++h) { f[h] = o[h]*inv; mu += f[h]; }
        mu *= 0.125f;
        float var = 0.f;
#pragma unroll
        for (int h = 0; h < 8; ++h) { const float d = f[h]-mu; var += d*d; }
        var *= 0.125f;
        const float rinv = rsqrtf(var + 1e-5f);
        float on[8];
#pragma unroll
        for (int h = 0; h < 8; ++h)
            on[h] = (f[h]-mu)*rinv*ln_g[h] + ln_b[h];
        float sv[3];
#pragma unroll
        for (int c = 0; c < 3; ++c) {
            float z = bp[c];
#pragma unroll
            for (int j = 0; j < 8; ++j) z += on[j]*Wp[j*3 + c];
            const float sp = (z > 20.f) ? z : log1pf(__expf(z));
            sv[c] = fminf(sp, 6.0f) + 1e-6f;
            sig[tok*3 + c] = sv[c];
        }
        atomicMax(smax, __float_as_int(fmaxf(sv[0], sv[1])));
    }
}

// ---------------- K4: bilateral filter (k_half folded in) ------------------
// one block per 16x16 patch; sigmas uniform within a patch.
// LDS tile stride 40 -> only the free 2-way (64 lanes / 32 banks) aliasing.
// Spatial weights precomputed once into LDS (k*k <= 289); range kernel via
// single exp2 with folded -0.5*log2(e)/sr^2 coefficient.
__global__ __launch_bounds__(256) void k_bilat(
    const float* __restrict__ x, const float* __restrict__ sig,
    int* __restrict__ smax, float* __restrict__ out)
{
    __shared__ float tile[32*40];
    __shared__ float spt[17*17];
    __shared__ int   s_half;

    const int blk = blockIdx.x;           // b*576 + n
    const int b  = blk / N_TOK;
    const int n  = blk % N_TOK;
    const int py = n / HP, px = n % HP;
    const int tx = threadIdx.x & 15, ty = threadIdx.x >> 4;

    if (threadIdx.x == 0) {
        // atomic RMW -> coherent cross-XCD read of k_attn2's atomicMax result
        const float m = __int_as_float(atomicMax(smax, 0));
        int h = (int)ceilf(m + 1.0f);
        if (h < 1) h = 1;
        if (h > 8) h = 8;                 // sigma cap 6 -> h <= 8 always
        s_half = h;
    }
    __syncthreads();
    const int half = s_half;
    const int k = 2*half + 1;
    const int tilew = PS + 2*half;        // <= 32

    const float sx = sig[blk*3 + 0];
    const float sy = sig[blk*3 + 1];
    const float sr = sig[blk*3 + 2];

    const float* xb = x + b*IMG*IMG;
    for (int yy = ty; yy < tilew; yy += 16) {
        const int gy = py*PS + yy - half;
        for (int xx = tx; xx < tilew; xx += 16) {
            const int gx = px*PS + xx - half;
            float v = 0.f;                // zero padding, included in sums
            if ((unsigned)gy < IMG && (unsigned)gx < IMG)
                v = xb[gy*IMG + gx];
            tile[yy*40 + xx] = v;
        }
    }
    {
        const float axc = -0.5f/(sx*sx);
        const float ayc = -0.5f/(sy*sy);
        for (int i = threadIdx.x; i < k*k; i += 256) {
            const int dy = i / k, dx = i - dy*k;
            const float fy = (float)(dy - half), fx = (float)(dx - half);
            spt[i] = __expf(ayc*fy*fy + axc*fx*fx);
        }
    }
    __syncthreads();

    const float c   = tile[(ty+half)*40 + (tx+half)];
    const float ar2 = -0.72134752044448170f/(sr*sr);   // -0.5*log2(e)/sr^2

    float num = 0.f, den = 0.f;
    for (int dy = 0; dy < k; ++dy) {
        const float* row = &tile[(ty+dy)*40 + tx];
        const float* spr = &spt[dy*k];    // lane-uniform -> LDS broadcast
        for (int dx = 0; dx < k; ++dx) {
            const float pix = row[dx];
            const float d   = c - pix;
            const float w   = spr[dx] * exp2f(ar2*d*d);
            den += w;
            num += w*pix;
        }
    }
    out[b*IMG*IMG + (py*PS + ty)*IMG + (px*PS + tx)] = num/(den + 1e-8f);
}

// ---------------- launch: 4 dispatches, no memset, no cooperative ----------
extern "C" void kernel_launch(void* const* d_in, const int* in_sizes, int n_in,
                              void* d_out, int out_size, void* d_ws, size_t ws_size,
                              hipStream_t stream)
{
    const float* x    = (const float*)d_in[0];
    const float* Wq   = (const float*)d_in[1];
    const float* bq   = (const float*)d_in[2];
    const float* Wk   = (const float*)d_in[3];
    const float* bk   = (const float*)d_in[4];
    const float* Wv   = (const float*)d_in[5];
    const float* bv   = (const float*)d_in[6];
    const float* Wsq  = (const float*)d_in[7];
    const float* bsq  = (const float*)d_in[8];
    const float* Wsk  = (const float*)d_in[9];
    const float* bsk  = (const float*)d_in[10];
    const float* Wsv  = (const float*)d_in[11];
    const float* bsv  = (const float*)d_in[12];
    const float* ln_g = (const float*)d_in[13];
    const float* ln_b = (const float*)d_in[14];
    const float* Wp   = (const float*)d_in[15];
    const float* bp   = (const float*)d_in[16];

    float* W  = (float*)d_ws;
    float* q1 = W;            // 2*576*8 = 9216 floats each
    float* k1 = W +  9216;
    float* v1 = W + 18432;
    float* q2 = W + 27648;
    float* k2 = W + 36864;
    float* v2 = W + 46080;
    float* sg = W + 55296;    // 2*576*3 = 3456
    int* smax = (int*)(W + 58752);

    k_qkv1<<<2*N_TOK/4, 256, 0, stream>>>(x, Wq, bq, Wk, bk, Wv, bv,
                                          q1, k1, v1, smax);
    k_attn1<<<2*N_TOK/4, 256, 0, stream>>>(q1, k1, v1, Wsq, bsq, Wsk, bsk,
                                           Wsv, bsv, q2, k2, v2);
    k_attn2<<<2*N_TOK/4, 256, 0, stream>>>(q2, k2, v2, ln_g, ln_b, Wp, bp,
                                           sg, smax);
    k_bilat<<<2*N_TOK, 256, 0, stream>>>(x, sg, smax, (float*)d_out);
}